// Round 9
// baseline (78.524 us; speedup 1.0000x reference)
//
#include <hip/hip_runtime.h>
#include <hip/hip_bf16.h>
#include <math.h>

typedef __bf16 bf16x8 __attribute__((ext_vector_type(8)));
typedef float  f32x4  __attribute__((ext_vector_type(4)));
typedef unsigned short u16x8 __attribute__((ext_vector_type(8)));

#define B_      16
#define LIN_    32768
#define LOUT_   32760
#define CIN_    21
#define CPAD_   24      // padded channels: row = 48B, 16B-aligned for b128
#define KT_     9
#define F_      128
#define KSTEPS_ 7       // R = 9*24 = 216 -> 7 x 32
#define TILE_L_ 128     // output rows per main block
#define ROWS_   136     // staged rows (128 + 8 overlap)
#define ROWSA_  138     // + 2 zero guard rows
#define NTILE_  256     // tiles per batch: 256*128 = 32768 covers 32760
#define OBST_   136     // outbuf row stride in floats (544B, 16B-aligned)

__device__ __forceinline__ unsigned short f2bf(float f) {
  unsigned u = __float_as_uint(f);
  u += 0x7FFFu + ((u >> 16) & 1u);   // RNE
  return (unsigned short)(u >> 16);
}
__device__ __forceinline__ float bf2f(unsigned short h) {
  return __uint_as_float(((unsigned)h) << 16);
}

// lgkmcnt-only barrier: does NOT drain vmem queues (loads/stores in flight)
__device__ __forceinline__ void bar_lds() {
  asm volatile("s_waitcnt lgkmcnt(0)" ::: "memory");
  __builtin_amdgcn_s_barrier();
}

// ---------------- prep: W fragment packing only (4 tiny blocks) ----------------
__global__ __launch_bounds__(256)
void ckn1d_prep(const float* __restrict__ W, float* __restrict__ ws)
{
  const int tid = threadIdx.x;
  const int wv  = blockIdx.x;              // 0..3
  unsigned short* Wp = (unsigned short*)ws;
  for (int idx = tid; idx < KSTEPS_ * 2 * 4 * 16; idx += 256) {
    int t   = idx >> 7;
    int rem = idx & 127;
    int nf  = rem >> 6;
    int q   = (rem >> 4) & 3;
    int la  = rem & 15;
    u16x8 v;
    #pragma unroll
    for (int j = 0; j < 8; ++j) {
      int r = t * 32 + q * 8 + j;
      int k = r / CPAD_;
      int c = r - k * CPAD_;
      float w = 0.f;
      if (c < CIN_ && k < KT_) w = W[(k * CIN_ + c) * F_ + wv * 32 + nf * 16 + la];
      v[j] = f2bf(w);
    }
    *(u16x8*)&Wp[(size_t)((((wv * KSTEPS_ + t) * 2 + nf) * 4 + q) * 16 + la) * 8] = v;
  }
}

// ---- main: stage + in-LDS energy (readback, no atomics) + MFMA +
//      outbuf epilogue with sequential float4 stores ----
__global__ __launch_bounds__(256, 4)
void ckn1d_main(const float* __restrict__ X, const float* __restrict__ ws,
                const float* __restrict__ scale_p, const float* __restrict__ bias_p,
                float* __restrict__ Y)
{
  __shared__ __align__(16) unsigned short tileA[ROWSA_ * CPAD_]; // 6624 B
  __shared__ __align__(16) float outbuf[32 * OBST_];             // 17408 B
  __shared__ float rowsq[ROWS_];                                 //  544 B
  __shared__ __align__(16) float inv_s[TILE_L_];                 //  512 B

  const int tid  = threadIdx.x;
  const int wv   = tid >> 6;
  const int lane = tid & 63;
  const int la   = lane & 15;
  const int q    = lane >> 4;

  const int bx   = blockIdx.x;
  const int b    = bx >> 8;
  const int tile = bx & (NTILE_ - 1);
  const int l0t  = tile * TILE_L_;

  const int f0 = wv * 32 + la;
  const float scale = scale_p[0];
  const float bias0 = bias_p[f0];
  const float bias1 = bias_p[f0 + 16];

  const float* __restrict__ Xb = X + (size_t)b * LIN_ * CIN_;
  const unsigned short* __restrict__ Wp = (const unsigned short*)ws;
  float* __restrict__ Yb = Y + (size_t)b * LOUT_ * F_;

  // ---- stage: zero pads + guards, then 136 rows x 21 ch -> bf16 LDS ----
  for (int i = tid; i < ROWSA_ * 3; i += 256) {
    int r = i / 3;
    tileA[r * CPAD_ + CIN_ + (i - r * 3)] = 0;
  }
  for (int i = tid; i < 2 * CIN_; i += 256) {
    int r = ROWS_ + i / CIN_;
    tileA[r * CPAD_ + (i % CIN_)] = 0;
  }
  {
    const float4* src4 = (const float4*)(Xb + (size_t)l0t * CIN_);
    const int n4v = (min(ROWS_, LIN_ - l0t) * CIN_) >> 2;
    for (int i4 = tid; i4 < (ROWS_ * CIN_) / 4; i4 += 256) {
      float4 v;
      if (i4 < n4v) v = src4[i4];
      else          v = make_float4(0.f, 0.f, 0.f, 0.f);
      int base = i4 * 4;
      #pragma unroll
      for (int e = 0; e < 4; ++e) {
        int idx = base + e;
        int r = idx / CIN_;
        int c = idx - r * CIN_;
        float x = (e == 0) ? v.x : (e == 1) ? v.y : (e == 2) ? v.z : v.w;
        tileA[r * CPAD_ + c] = f2bf(x);
      }
    }
  }

  // ---- B fragments: 14 coalesced 16B loads from L2-hot Wp ----
  u16x8 bw[KSTEPS_][2];
  #pragma unroll
  for (int t = 0; t < KSTEPS_; ++t)
    #pragma unroll
    for (int nf = 0; nf < 2; ++nf)
      bw[t][nf] = *(const u16x8*)&Wp[(size_t)((((wv * KSTEPS_ + t) * 2 + nf) * 4 + q) * 16 + la) * 8];

  bar_lds();   // staging complete

  // ---- energy: per-row sum of squares from bf16 tileA (no atomics) ----
  if (tid < ROWS_) {
    const u16x8* rp = (const u16x8*)&tileA[tid * CPAD_];
    float s = 0.f;
    #pragma unroll
    for (int g = 0; g < 3; ++g) {
      u16x8 v = rp[g];
      #pragma unroll
      for (int j = 0; j < 8; ++j) { float x = bf2f(v[j]); s += x * x; }
    }
    rowsq[tid] = s;
  }
  bar_lds();

  // ---- sliding 9-row energy -> scale/(sqrt(e+eps)+eps) ----
  if (tid < TILE_L_) {
    float e = 0.f;
    #pragma unroll
    for (int t = 0; t < KT_; ++t) e += rowsq[tid + t];
    inv_s[tid] = scale / (sqrtf(e + 1e-5f) + 1e-5f);
  }
  bar_lds();   // inv_s visible

  const f32x4 fzero = {0.f, 0.f, 0.f, 0.f};

  // ---- mf-pair loop: compute 32 rows, round-trip via outbuf, store seq ----
  #pragma unroll 1
  for (int mp = 0; mp < 4; ++mp) {
    f32x4 acc[2][2];   // [mf-in-pair][nf]
    #pragma unroll
    for (int mfl = 0; mfl < 2; ++mfl) {
      const int mf = mp * 2 + mfl;
      acc[mfl][0] = fzero; acc[mfl][1] = fzero;
      const unsigned short* arow = &tileA[(mf * 16 + la) * CPAD_ + q * 8];
      #pragma unroll
      for (int t = 0; t < KSTEPS_; ++t) {
        bf16x8 a = *(const bf16x8*)&arow[t * 32];
        acc[mfl][0] = __builtin_amdgcn_mfma_f32_16x16x32_bf16(
            a, __builtin_bit_cast(bf16x8, bw[t][0]), acc[mfl][0], 0, 0, 0);
        acc[mfl][1] = __builtin_amdgcn_mfma_f32_16x16x32_bf16(
            a, __builtin_bit_cast(bf16x8, bw[t][1]), acc[mfl][1], 0, 0, 0);
      }
    }

    if (mp > 0) bar_lds();   // previous pair's outbuf readers done

    // acc -> outbuf (scaled + biased). C layout: col=la, row=q*4+rg.
    #pragma unroll
    for (int mfl = 0; mfl < 2; ++mfl) {
      const int lrow0 = mfl * 16 + q * 4;          // 0..31 within pair
      const f32x4 iv4 = *(const f32x4*)&inv_s[mp * 32 + lrow0];
      #pragma unroll
      for (int rg = 0; rg < 4; ++rg) {
        float iv = iv4[rg];
        outbuf[(lrow0 + rg) * OBST_ + f0]      = acc[mfl][0][rg] * iv + bias0;
        outbuf[(lrow0 + rg) * OBST_ + f0 + 16] = acc[mfl][1][rg] * iv + bias1;
      }
    }
    bar_lds();   // outbuf visible

    // store: 1KB-sequential float4 per wave-instr (2 full 512B rows)
    {
      const int lg0 = l0t + mp * 32;
      #pragma unroll
      for (int it = 0; it < 4; ++it) {
        int i  = tid + it * 256;
        int r  = i >> 5;          // 0..31
        int c4 = i & 31;
        int lg = lg0 + r;
        if (lg < LOUT_) {
          float4 v = *(const float4*)&outbuf[r * OBST_ + c4 * 4];
          *(float4*)&Yb[(size_t)lg * F_ + c4 * 4] = v;
        }
      }
    }
  }
}

extern "C" void kernel_launch(void* const* d_in, const int* in_sizes, int n_in,
                              void* d_out, int out_size, void* d_ws, size_t ws_size,
                              hipStream_t stream) {
  const float* X  = (const float*)d_in[0];
  const float* W  = (const float*)d_in[1];
  const float* S  = (const float*)d_in[2];
  const float* Bi = (const float*)d_in[3];
  float* Y  = (float*)d_out;
  float* ws = (float*)d_ws;

  ckn1d_prep<<<dim3(4), dim3(256), 0, stream>>>(W, ws);
  ckn1d_main<<<dim3(B_ * NTILE_), dim3(256), 0, stream>>>(X, ws, S, Bi, Y);
}

// Round 10
// 71.533 us; speedup vs baseline: 1.0977x; 1.0977x over previous
//
#include <hip/hip_runtime.h>
#include <hip/hip_bf16.h>
#include <math.h>

typedef __bf16 bf16x8 __attribute__((ext_vector_type(8)));
typedef float  f32x4  __attribute__((ext_vector_type(4)));
typedef unsigned short u16x8 __attribute__((ext_vector_type(8)));

#define B_      16
#define LIN_    32768
#define LOUT_   32760
#define CIN_    21
#define CPAD_   24      // padded channels: row = 48B, 16B-aligned for b128
#define KT_     9
#define F_      128
#define KSTEPS_ 7       // R = 9*24 = 216 -> 7 x 32
#define TILE_L_ 128     // output rows per main block
#define ROWS_   136     // staged rows (128 + 8 overlap)
#define ROWSA_  138     // + 2 zero guard rows
#define NTILE_  256     // tiles per batch
#define LPAD_   32768   // per-batch inv_s stride in ws
#define OBST_   136     // outbuf row stride in floats (544B)
// prep inv blocks: 512 outputs each, f32 LDS staging
#define IBR_    512
#define NIB_    (B_ * (LIN_ / IBR_))     // 16 * 64 = 1024
// ws layout: [0, 16*32768) floats = inv_s ; then Wp (bf16 fragments)
#define WP_OFF_FLOATS_ (B_ * LPAD_)

__device__ __forceinline__ unsigned short f2bf(float f) {
  unsigned u = __float_as_uint(f);
  u += 0x7FFFu + ((u >> 16) & 1u);   // RNE
  return (unsigned short)(u >> 16);
}

// lgkmcnt-only barrier: does NOT drain vmem queues (stores stay in flight)
__device__ __forceinline__ void bar_lds() {
  asm volatile("s_waitcnt lgkmcnt(0)" ::: "memory");
  __builtin_amdgcn_s_barrier();
}

// ---------------- prep: coalesced inv_s + W fragment packing ----------------
__global__ __launch_bounds__(256, 3)
void ckn1d_prep(const float* __restrict__ X, const float* __restrict__ W,
                const float* __restrict__ scale_p, float* __restrict__ ws)
{
  const int tid = threadIdx.x;
  const int bid = blockIdx.x;

  if (bid < NIB_) {
    // ---- inv block: stage 520 rows f32 -> LDS (float4 coalesced) ----
    __shared__ __align__(16) float xs[(IBR_ + 8) * CIN_];   // 43680 B
    __shared__ float rowsq[IBR_ + 8];                       //  2080 B
    const int b    = bid >> 6;
    const int base = (bid & 63) * IBR_;
    const float scale = scale_p[0];
    const float* src = X + ((size_t)b * LIN_ + base) * CIN_;  // 16B-aligned
    const int nval4 = (min(IBR_ + 8, LIN_ - base) * CIN_) >> 2;
    const float4* src4 = (const float4*)src;
    // (IBR_+8)*CIN_ = 10920 floats = 2730 float4, no remainder
    for (int i = tid; i < ((IBR_ + 8) * CIN_) / 4; i += 256) {
      float4 v = (i < nval4) ? src4[i] : make_float4(0.f, 0.f, 0.f, 0.f);
      *(float4*)&xs[i * 4] = v;
    }
    __syncthreads();

    // row sums: stride-21-dword rows -> 21 coprime to 32 -> 2-way max (free)
    for (int r = tid; r < IBR_ + 8; r += 256) {
      const float* xr = &xs[r * CIN_];
      float s = 0.f;
      #pragma unroll
      for (int c = 0; c < CIN_; ++c) { float x = xr[c]; s += x * x; }
      rowsq[r] = s;
    }
    __syncthreads();

    // sliding 9-row window -> inv; coalesced scalar stores
    #pragma unroll
    for (int h = 0; h < IBR_ / 256; ++h) {
      int l = tid + h * 256;
      float e = 0.f;
      #pragma unroll
      for (int t = 0; t < KT_; ++t) e += rowsq[l + t];
      int gl = base + l;
      if (gl < LOUT_)
        ws[(size_t)b * LPAD_ + gl] = scale / (sqrtf(e + 1e-5f) + 1e-5f);
    }
  } else {
    // ---- W packing block: one per wave-role wv ----
    const int wv = bid - NIB_;               // 0..3
    unsigned short* Wp = (unsigned short*)(ws + WP_OFF_FLOATS_);
    for (int idx = tid; idx < KSTEPS_ * 2 * 4 * 16; idx += 256) {
      int t   = idx >> 7;
      int rem = idx & 127;
      int nf  = rem >> 6;
      int q   = (rem >> 4) & 3;
      int la  = rem & 15;
      u16x8 v;
      #pragma unroll
      for (int j = 0; j < 8; ++j) {
        int r = t * 32 + q * 8 + j;
        int k = r / CPAD_;
        int c = r - k * CPAD_;
        float w = 0.f;
        if (c < CIN_ && k < KT_) w = W[(k * CIN_ + c) * F_ + wv * 32 + nf * 16 + la];
        v[j] = f2bf(w);
      }
      *(u16x8*)&Wp[(size_t)((((wv * KSTEPS_ + t) * 2 + nf) * 4 + q) * 16 + la) * 8] = v;
    }
  }
}

// ---- main: stage + MFMA + outbuf epilogue with sequential float4 stores ----
// (exact R8 structure: best known, 69.09 us)
__global__ __launch_bounds__(256, 4)
void ckn1d_main(const float* __restrict__ X, const float* __restrict__ ws,
                const float* __restrict__ bias_p, float* __restrict__ Y)
{
  __shared__ __align__(16) unsigned short tileA[ROWSA_ * CPAD_]; // 6624 B
  __shared__ __align__(16) float outbuf[32 * OBST_];             // 17408 B

  const int tid  = threadIdx.x;
  const int wv   = tid >> 6;
  const int lane = tid & 63;
  const int la   = lane & 15;
  const int q    = lane >> 4;

  const int bx   = blockIdx.x;
  const int b    = bx >> 8;
  const int tile = bx & (NTILE_ - 1);
  const int l0t  = tile * TILE_L_;

  const int f0 = wv * 32 + la;
  const float bias0 = bias_p[f0];
  const float bias1 = bias_p[f0 + 16];

  const float* __restrict__ Xb   = X + (size_t)b * LIN_ * CIN_;
  const float* __restrict__ invb = ws + (size_t)b * LPAD_ + l0t;
  const unsigned short* __restrict__ Wp = (const unsigned short*)(ws + WP_OFF_FLOATS_);
  float* __restrict__ Yb = Y + (size_t)b * LOUT_ * F_;

  // ---- stage: zero pads + guards, then 136 rows x 21 ch -> bf16 LDS ----
  for (int i = tid; i < ROWSA_ * 3; i += 256) {
    int r = i / 3;
    tileA[r * CPAD_ + CIN_ + (i - r * 3)] = 0;
  }
  for (int i = tid; i < 2 * CIN_; i += 256) {
    int r = ROWS_ + i / CIN_;
    tileA[r * CPAD_ + (i % CIN_)] = 0;
  }
  {
    const float4* src4 = (const float4*)(Xb + (size_t)l0t * CIN_);
    const int n4v = (min(ROWS_, LIN_ - l0t) * CIN_) >> 2;
    for (int i4 = tid; i4 < (ROWS_ * CIN_) / 4; i4 += 256) {
      float4 v;
      if (i4 < n4v) v = src4[i4];
      else          v = make_float4(0.f, 0.f, 0.f, 0.f);
      int base = i4 * 4;
      #pragma unroll
      for (int e = 0; e < 4; ++e) {
        int idx = base + e;
        int r = idx / CIN_;
        int c = idx - r * CIN_;
        float x = (e == 0) ? v.x : (e == 1) ? v.y : (e == 2) ? v.z : v.w;
        tileA[r * CPAD_ + c] = f2bf(x);
      }
    }
  }

  // ---- B fragments: 14 coalesced 16B loads from L2-hot Wp ----
  u16x8 bw[KSTEPS_][2];
  #pragma unroll
  for (int t = 0; t < KSTEPS_; ++t)
    #pragma unroll
    for (int nf = 0; nf < 2; ++nf)
      bw[t][nf] = *(const u16x8*)&Wp[(size_t)((((wv * KSTEPS_ + t) * 2 + nf) * 4 + q) * 16 + la) * 8];

  bar_lds();   // staging complete

  const f32x4 fzero = {0.f, 0.f, 0.f, 0.f};

  // ---- mf-pair loop: compute 32 rows, round-trip via outbuf, store seq ----
  #pragma unroll 1
  for (int mp = 0; mp < 4; ++mp) {
    f32x4 acc[2][2];   // [mf-in-pair][nf]
    #pragma unroll
    for (int mfl = 0; mfl < 2; ++mfl) {
      const int mf = mp * 2 + mfl;
      acc[mfl][0] = fzero; acc[mfl][1] = fzero;
      const unsigned short* arow = &tileA[(mf * 16 + la) * CPAD_ + q * 8];
      #pragma unroll
      for (int t = 0; t < KSTEPS_; ++t) {
        bf16x8 a = *(const bf16x8*)&arow[t * 32];
        acc[mfl][0] = __builtin_amdgcn_mfma_f32_16x16x32_bf16(
            a, __builtin_bit_cast(bf16x8, bw[t][0]), acc[mfl][0], 0, 0, 0);
        acc[mfl][1] = __builtin_amdgcn_mfma_f32_16x16x32_bf16(
            a, __builtin_bit_cast(bf16x8, bw[t][1]), acc[mfl][1], 0, 0, 0);
      }
    }

    if (mp > 0) bar_lds();   // previous pair's outbuf readers done

    // acc -> outbuf (scaled + biased). C layout: col=la, row=q*4+rg.
    #pragma unroll
    for (int mfl = 0; mfl < 2; ++mfl) {
      const int lrow0 = mfl * 16 + q * 4;          // 0..31 within pair
      const f32x4 iv4 = *(const f32x4*)&invb[mp * 32 + lrow0];
      #pragma unroll
      for (int rg = 0; rg < 4; ++rg) {
        float iv = iv4[rg];
        outbuf[(lrow0 + rg) * OBST_ + f0]      = acc[mfl][0][rg] * iv + bias0;
        outbuf[(lrow0 + rg) * OBST_ + f0 + 16] = acc[mfl][1][rg] * iv + bias1;
      }
    }
    bar_lds();   // outbuf visible

    // store: 1KB-sequential float4 per wave-instr (2 full 512B rows)
    {
      const int lg0 = l0t + mp * 32;
      #pragma unroll
      for (int it = 0; it < 4; ++it) {
        int i  = tid + it * 256;
        int r  = i >> 5;          // 0..31
        int c4 = i & 31;
        int lg = lg0 + r;
        if (lg < LOUT_) {
          float4 v = *(const float4*)&outbuf[r * OBST_ + c4 * 4];
          *(float4*)&Yb[(size_t)lg * F_ + c4 * 4] = v;
        }
      }
    }
  }
}

extern "C" void kernel_launch(void* const* d_in, const int* in_sizes, int n_in,
                              void* d_out, int out_size, void* d_ws, size_t ws_size,
                              hipStream_t stream) {
  const float* X  = (const float*)d_in[0];
  const float* W  = (const float*)d_in[1];
  const float* S  = (const float*)d_in[2];
  const float* Bi = (const float*)d_in[3];
  float* Y  = (float*)d_out;
  float* ws = (float*)d_ws;

  ckn1d_prep<<<dim3(NIB_ + 4), dim3(256), 0, stream>>>(X, W, S, ws);
  ckn1d_main<<<dim3(B_ * NTILE_), dim3(256), 0, stream>>>(X, ws, Bi, Y);
}

// Round 11
// 68.836 us; speedup vs baseline: 1.1407x; 1.0392x over previous
//
#include <hip/hip_runtime.h>
#include <hip/hip_bf16.h>
#include <math.h>

typedef __bf16 bf16x8 __attribute__((ext_vector_type(8)));
typedef float  f32x4  __attribute__((ext_vector_type(4)));
typedef unsigned short u16x8 __attribute__((ext_vector_type(8)));

#define B_      16
#define LIN_    32768
#define LOUT_   32760
#define CIN_    21
#define CPAD_   24      // padded channels: row = 48B, 16B-aligned for b128
#define KT_     9
#define F_      128
#define KSTEPS_ 7       // R = 9*24 = 216 -> 7 x 32
#define TILE_L_ 128     // output rows per main block
#define ROWS_   136     // staged rows (128 + 8 overlap)
#define ROWSA_  138     // + 2 zero guard rows
#define NTILE_  256     // tiles per batch: 256*128 = 32768 covers 32760
#define LPAD_   32768   // per-batch inv_s stride in ws (padded)
#define OBST_   136     // outbuf row stride in floats (544B, 16B-aligned)
// prep: inv blocks
#define IB_ROWS_ 1024
#define IB_PER_B 32
// ws layout: [0, 16*32768) floats = inv_s ; then Wp (bf16 fragments)
#define WP_OFF_FLOATS_ (B_ * LPAD_)

__device__ __forceinline__ unsigned short f2bf(float f) {
  unsigned u = __float_as_uint(f);
  u += 0x7FFFu + ((u >> 16) & 1u);   // RNE
  return (unsigned short)(u >> 16);
}

// lgkmcnt-only barrier: does NOT drain vmem queues (stores stay in flight)
__device__ __forceinline__ void bar_lds() {
  asm volatile("s_waitcnt lgkmcnt(0)" ::: "memory");
  __builtin_amdgcn_s_barrier();
}

// ---------------- prep: inv_s for all rows + W fragment packing ----------------
__global__ __launch_bounds__(256)
void ckn1d_prep(const float* __restrict__ X, const float* __restrict__ W,
                const float* __restrict__ scale_p, float* __restrict__ ws)
{
  const int tid = threadIdx.x;
  const int bid = blockIdx.x;

  if (bid < B_ * IB_PER_B) {
    __shared__ float rowsq[IB_ROWS_ + 8];
    const int b    = bid >> 5;
    const int base = (bid & (IB_PER_B - 1)) * IB_ROWS_;
    const float scale = scale_p[0];
    const float* Xb = X + (size_t)b * LIN_ * CIN_;

    for (int r = tid; r < IB_ROWS_ + 8; r += 256) {
      int row = base + r;
      float s = 0.f;
      if (row < LIN_) {
        const float* xr = Xb + (size_t)row * CIN_;
        #pragma unroll
        for (int c = 0; c < CIN_; ++c) { float x = xr[c]; s += x * x; }
      }
      rowsq[r] = s;
    }
    __syncthreads();

    const int l0 = tid * 4;
    float e0 = 0.f;
    #pragma unroll
    for (int t = 0; t < KT_; ++t) e0 += rowsq[l0 + t];
    float e1 = e0 - rowsq[l0]     + rowsq[l0 + KT_];
    float e2 = e1 - rowsq[l0 + 1] + rowsq[l0 + 1 + KT_];
    float e3 = e2 - rowsq[l0 + 2] + rowsq[l0 + 2 + KT_];
    f32x4 iv;
    iv[0] = scale / (sqrtf(e0 + 1e-5f) + 1e-5f);
    iv[1] = scale / (sqrtf(e1 + 1e-5f) + 1e-5f);
    iv[2] = scale / (sqrtf(e2 + 1e-5f) + 1e-5f);
    iv[3] = scale / (sqrtf(e3 + 1e-5f) + 1e-5f);
    float* invp = ws + (size_t)b * LPAD_ + base + l0;
    if (base + l0 + 3 < LOUT_) {
      *(f32x4*)invp = iv;
    } else {
      #pragma unroll
      for (int u = 0; u < 4; ++u)
        if (base + l0 + u < LOUT_) invp[u] = iv[u];
    }
  } else {
    const int wv = bid - B_ * IB_PER_B;      // 0..3
    unsigned short* Wp = (unsigned short*)(ws + WP_OFF_FLOATS_);
    for (int idx = tid; idx < KSTEPS_ * 2 * 4 * 16; idx += 256) {
      int t   = idx >> 7;
      int rem = idx & 127;
      int nf  = rem >> 6;
      int q   = (rem >> 4) & 3;
      int la  = rem & 15;
      u16x8 v;
      #pragma unroll
      for (int j = 0; j < 8; ++j) {
        int r = t * 32 + q * 8 + j;
        int k = r / CPAD_;
        int c = r - k * CPAD_;
        float w = 0.f;
        if (c < CIN_ && k < KT_) w = W[(k * CIN_ + c) * F_ + wv * 32 + nf * 16 + la];
        v[j] = f2bf(w);
      }
      *(u16x8*)&Wp[(size_t)((((wv * KSTEPS_ + t) * 2 + nf) * 4 + q) * 16 + la) * 8] = v;
    }
  }
}

// ---- main: stage + MFMA + outbuf epilogue with sequential float4 stores ----
__global__ __launch_bounds__(256, 4)
void ckn1d_main(const float* __restrict__ X, const float* __restrict__ ws,
                const float* __restrict__ bias_p, float* __restrict__ Y)
{
  __shared__ __align__(16) unsigned short tileA[ROWSA_ * CPAD_]; // 6624 B
  __shared__ __align__(16) float outbuf[32 * OBST_];             // 17408 B

  const int tid  = threadIdx.x;
  const int wv   = tid >> 6;
  const int lane = tid & 63;
  const int la   = lane & 15;
  const int q    = lane >> 4;

  const int bx   = blockIdx.x;
  const int b    = bx >> 8;
  const int tile = bx & (NTILE_ - 1);
  const int l0t  = tile * TILE_L_;

  const int f0 = wv * 32 + la;
  const float bias0 = bias_p[f0];
  const float bias1 = bias_p[f0 + 16];

  const float* __restrict__ Xb   = X + (size_t)b * LIN_ * CIN_;
  const float* __restrict__ invb = ws + (size_t)b * LPAD_ + l0t;
  const unsigned short* __restrict__ Wp = (const unsigned short*)(ws + WP_OFF_FLOATS_);
  float* __restrict__ Yb = Y + (size_t)b * LOUT_ * F_;

  // ---- stage: zero pads, then 136 rows x 21 ch -> bf16 LDS ----
  for (int i = tid; i < ROWSA_ * 3; i += 256) {
    int r = i / 3;
    tileA[r * CPAD_ + CIN_ + (i - r * 3)] = 0;
  }
  for (int i = tid; i < 2 * CIN_; i += 256) {
    int r = ROWS_ + i / CIN_;
    tileA[r * CPAD_ + (i % CIN_)] = 0;
  }
  {
    const float4* src4 = (const float4*)(Xb + (size_t)l0t * CIN_);
    const int n4v = (min(ROWS_, LIN_ - l0t) * CIN_) >> 2;
    for (int i4 = tid; i4 < (ROWS_ * CIN_) / 4; i4 += 256) {
      float4 v;
      if (i4 < n4v) v = src4[i4];
      else          v = make_float4(0.f, 0.f, 0.f, 0.f);
      int base = i4 * 4;
      #pragma unroll
      for (int e = 0; e < 4; ++e) {
        int idx = base + e;
        int r = idx / CIN_;
        int c = idx - r * CIN_;
        float x = (e == 0) ? v.x : (e == 1) ? v.y : (e == 2) ? v.z : v.w;
        tileA[r * CPAD_ + c] = f2bf(x);
      }
    }
  }

  // ---- B fragments: 14 coalesced 16B loads from L2-hot Wp ----
  u16x8 bw[KSTEPS_][2];
  #pragma unroll
  for (int t = 0; t < KSTEPS_; ++t)
    #pragma unroll
    for (int nf = 0; nf < 2; ++nf)
      bw[t][nf] = *(const u16x8*)&Wp[(size_t)((((wv * KSTEPS_ + t) * 2 + nf) * 4 + q) * 16 + la) * 8];

  bar_lds();   // staging complete

  const f32x4 fzero = {0.f, 0.f, 0.f, 0.f};

  // ---- mf-pair loop: compute 32 rows, round-trip via outbuf, store seq ----
  #pragma unroll 1
  for (int mp = 0; mp < 4; ++mp) {
    f32x4 acc[2][2];   // [mf-in-pair][nf]
    #pragma unroll
    for (int mfl = 0; mfl < 2; ++mfl) {
      const int mf = mp * 2 + mfl;
      acc[mfl][0] = fzero; acc[mfl][1] = fzero;
      const unsigned short* arow = &tileA[(mf * 16 + la) * CPAD_ + q * 8];
      #pragma unroll
      for (int t = 0; t < KSTEPS_; ++t) {
        bf16x8 a = *(const bf16x8*)&arow[t * 32];
        acc[mfl][0] = __builtin_amdgcn_mfma_f32_16x16x32_bf16(
            a, __builtin_bit_cast(bf16x8, bw[t][0]), acc[mfl][0], 0, 0, 0);
        acc[mfl][1] = __builtin_amdgcn_mfma_f32_16x16x32_bf16(
            a, __builtin_bit_cast(bf16x8, bw[t][1]), acc[mfl][1], 0, 0, 0);
      }
    }

    if (mp > 0) bar_lds();   // previous pair's outbuf readers done

    // acc -> outbuf (scaled + biased). C layout: col=la, row=q*4+rg.
    #pragma unroll
    for (int mfl = 0; mfl < 2; ++mfl) {
      const int lrow0 = mfl * 16 + q * 4;          // 0..31 within pair
      const f32x4 iv4 = *(const f32x4*)&invb[mp * 32 + lrow0];
      #pragma unroll
      for (int rg = 0; rg < 4; ++rg) {
        float iv = iv4[rg];
        outbuf[(lrow0 + rg) * OBST_ + f0]      = acc[mfl][0][rg] * iv + bias0;
        outbuf[(lrow0 + rg) * OBST_ + f0 + 16] = acc[mfl][1][rg] * iv + bias1;
      }
    }
    bar_lds();   // outbuf visible

    // store: 1KB-sequential float4 per wave-instr (2 full 512B rows)
    {
      const int lg0 = l0t + mp * 32;
      #pragma unroll
      for (int it = 0; it < 4; ++it) {
        int i  = tid + it * 256;
        int r  = i >> 5;          // 0..31
        int c4 = i & 31;
        int lg = lg0 + r;
        if (lg < LOUT_) {
          float4 v = *(const float4*)&outbuf[r * OBST_ + c4 * 4];
          *(float4*)&Yb[(size_t)lg * F_ + c4 * 4] = v;
        }
      }
    }
  }
}

extern "C" void kernel_launch(void* const* d_in, const int* in_sizes, int n_in,
                              void* d_out, int out_size, void* d_ws, size_t ws_size,
                              hipStream_t stream) {
  const float* X  = (const float*)d_in[0];
  const float* W  = (const float*)d_in[1];
  const float* S  = (const float*)d_in[2];
  const float* Bi = (const float*)d_in[3];
  float* Y  = (float*)d_out;
  float* ws = (float*)d_ws;

  dim3 gprep(B_ * IB_PER_B + 4), block(256);
  ckn1d_prep<<<gprep, block, 0, stream>>>(X, W, S, ws);

  dim3 gmain(B_ * NTILE_);
  ckn1d_main<<<gmain, block, 0, stream>>>(X, ws, Bi, Y);
}